// Round 5
// baseline (73.381 us; speedup 1.0000x reference)
//
#include <hip/hip_runtime.h>
#include <hip/hip_bf16.h>
#include <math.h>

// TokenCompressor: B=8, N=16384, C=128, BLOCK=32, STRIDE=16 -> nb=1023
// Decomposition: chunks c of 16 tokens; A = x.view(8192, 2048) (contiguous!)
//   P[m, 0:256]  = chunk[m] @ W1[0:2048]
//   P[m, 256:512]= chunk[m] @ W1[2048:4096]
//   h[j] = gelu(P[j,0:256] + P[j+1,256:512] + b1 + posflat@W1)
//   out[j] = h[j] @ W2 + b2
// R5: THE fix per R4 post-mortem: __syncthreads() drains vmcnt(0) -> the
// next-tile loads issued in the same iteration were waited on EVERY K-step
// (full L2/HBM latency exposed 8x/block). Replace with raw s_barrier +
// counted "s_waitcnt vmcnt(12)" (T4): the 12 loads issued this iteration
// stay in flight across the barrier; only the previous iteration's B-DMA
// (covered by a full compute phase) must have landed.

typedef __attribute__((ext_vector_type(8))) short short8;
typedef __attribute__((ext_vector_type(4))) float f4;

#define OFF_BT   0u                          // 512x2048 bf16 = 2 MB
#define OFF_W2T  (2u << 20)                  // 128x256 bf16 = 64 KB
#define OFF_PART ((2u << 20) + (64u << 10))  // 64x256 f32 = 64 KB
#define OFF_BIAS ((2u << 20) + (128u << 10)) // 256 f32
#define OFF_P    (4u << 20)                  // 4 x (8192x512) bf16 = 32 MB

static __device__ __forceinline__ unsigned short f2bf(float f) {
  union { float f; unsigned u; } v; v.f = f;
  return (unsigned short)((v.u + 0x7FFFu + ((v.u >> 16) & 1u)) >> 16);
}
static __device__ __forceinline__ float bf2f(unsigned short h) {
  union { unsigned u; float f; } v; v.u = ((unsigned)h) << 16;
  return v.f;
}
static __device__ __forceinline__ void gload_lds16(const void* g, void* l) {
  __builtin_amdgcn_global_load_lds(
      (const __attribute__((address_space(1))) void*)g,
      (__attribute__((address_space(3))) void*)l, 16, 0, 0);
}

// ---- k_prep: blocks 0..255: W1 -> Bt (512x2048 bf16, n-major) + bias parts
//              blocks 256..383: W2 (256x128 f32) -> W2t (128x256 bf16, T)
__global__ __launch_bounds__(256) void k_prep(const float* __restrict__ W1,
                                              const float* __restrict__ pos,
                                              const float* __restrict__ W2,
                                              unsigned short* __restrict__ Bt,
                                              unsigned short* __restrict__ W2t,
                                              float* __restrict__ part) {
  __shared__ float T[64][65];
  const int w = blockIdx.x;
  const int t = threadIdx.x;
  if (w >= 256) {
    const int n = w - 256;
    W2t[n * 256 + t] = f2bf(W2[t * 128 + n]);
    return;
  }
  const int h = w >> 7, rem = w & 127, kt = rem >> 2, nt = rem & 3;
  const int krow0 = h * 2048 + kt * 64, col0 = nt * 64;
  const int lr = t >> 2, lc = (t & 3) * 16;
  const float* src = W1 + (size_t)(krow0 + lr) * 256 + col0 + lc;
#pragma unroll
  for (int i = 0; i < 4; ++i) {
    f4 v = *(const f4*)(src + i * 4);
#pragma unroll
    for (int q = 0; q < 4; ++q) T[lr][lc + i * 4 + q] = v[q];
  }
  __syncthreads();
  if (t < 64) {
    float s = 0.f;
#pragma unroll 8
    for (int k = 0; k < 64; ++k) s += T[k][t] * pos[krow0 + k];
    part[(h * 32 + kt) * 256 + col0 + t] = s;
  }
  const int nl = t >> 2, kc = (t & 3) * 16;
  short8 o0, o1;
#pragma unroll
  for (int i = 0; i < 8; ++i) o0[i] = (short)f2bf(T[kc + i][nl]);
#pragma unroll
  for (int i = 0; i < 8; ++i) o1[i] = (short)f2bf(T[kc + 8 + i][nl]);
  unsigned short* dst = Bt + (size_t)(256 * h + col0 + nl) * 2048 + kt * 64 + kc;
  *(short8*)dst = o0;
  *(short8*)(dst + 8) = o1;
}

// ---- k_bias ------------------------------------------------------------
__global__ __launch_bounds__(256) void k_bias(const float* __restrict__ b1,
                                              const float* __restrict__ part,
                                              float* __restrict__ bias) {
  int n = threadIdx.x;
  float s = b1[n];
#pragma unroll 8
  for (int g = 0; g < 64; ++g) s += part[g * 256 + n];
  bias[n] = s;
}

// ---- k_gemm: Ppart[ks] (8192x512 bf16) = A(f32)[:,ks*512:+512] @ Bt^T ----
// 128x128 tile, BK=64, 8 kt. 4 waves x (64x64). 1024 wgs.
// Counted-vmcnt pipeline: raw s_barrier, never vmcnt(0) in main loop.
__global__ __launch_bounds__(256, 2) void k_gemm(const float* __restrict__ X,
                                                 const unsigned short* __restrict__ Bt,
                                                 unsigned short* __restrict__ P) {
  __shared__ unsigned short As[2][128 * 64];
  __shared__ unsigned short Bs[2][128 * 64];
  const int orig = blockIdx.x;
  const int wg = (orig & 7) * 128 + (orig >> 3);  // 1024 % 8 == 0 -> bijective
  const int mt = wg >> 4;                 // 0..63
  const int nt = (wg >> 2) & 3;           // 0..3
  const int ks_split = wg & 3;            // 0..3
  const int m0 = mt * 128, n0 = nt * 128;
  const int k0 = ks_split * 512;
  const int t = threadIdx.x;
  const int wid = t >> 6, lane = t & 63;
  const int wm = (wid >> 1) * 64, wn = (wid & 1) * 64;
  const int sr = t >> 1;           // A staging row 0..127
  const int sc = (t & 1) * 32;     // A f32 col offset
  const int cb = (t & 1) * 4;      // A 16B-chunk base
  const float* Ag = X + (size_t)(m0 + sr) * 2048 + k0 + sc;

  f4 acc[4][4];
#pragma unroll
  for (int i = 0; i < 4; ++i)
#pragma unroll
    for (int j = 0; j < 4; ++j) acc[i][j] = f4{0.f, 0.f, 0.f, 0.f};

  f4 ra0[8], ra1[8];

#define A_LOAD(RS, KT)                                                    \
  do {                                                                    \
    const float* ap = Ag + (KT) * 64;                                     \
    _Pragma("unroll") for (int i = 0; i < 8; ++i)                         \
        RS[i] = *(const f4*)(ap + i * 4);                                 \
  } while (0)

#define A_STORE(RS, BUF)                                                  \
  do {                                                                    \
    _Pragma("unroll") for (int i = 0; i < 4; ++i) {                       \
      short8 pk;                                                          \
      _Pragma("unroll") for (int q = 0; q < 8; ++q)                       \
          pk[q] = (short)f2bf(RS[i * 2 + (q >> 2)][q & 3]);               \
      const int c = (cb + i) ^ (sr & 7);                                  \
      *(short8*)&As[BUF][sr * 64 + c * 8] = pk;                           \
    }                                                                     \
  } while (0)

  // B DMA: LDS slot (r,c) holds global chunk c^(r&7); per-wave uniform base.
#define B_ISSUE(BUF, KT)                                                  \
  do {                                                                    \
    const size_t kofs = (size_t)k0 + (size_t)(KT) * 64;                   \
    _Pragma("unroll") for (int ii = 0; ii < 4; ++ii) {                    \
      const int rr = ii * 32 + (t >> 3);                                  \
      const int ch = (t & 7) ^ (rr & 7);                                  \
      const unsigned short* gsrc =                                        \
          Bt + (size_t)(n0 + rr) * 2048 + kofs + ch * 8;                  \
      char* ldst = ((char*)&Bs[BUF][0]) + ii * 4096 + wid * 1024;         \
      gload_lds16(gsrc, ldst);                                            \
    }                                                                     \
  } while (0)

#define COMPUTE(BUF)                                                      \
  do {                                                                    \
    _Pragma("unroll") for (int ks = 0; ks < 2; ++ks) {                    \
      short8 af[4], bfv[4];                                               \
      const int cc = ks * 4 + (lane >> 4);                                \
      _Pragma("unroll") for (int f = 0; f < 4; ++f) {                     \
        const int raA = wm + f * 16 + (lane & 15);                        \
        af[f] = *(const short8*)&As[BUF][raA * 64 + ((cc ^ (raA & 7)) << 3)]; \
        const int rbB = wn + f * 16 + (lane & 15);                        \
        bfv[f] = *(const short8*)&Bs[BUF][rbB * 64 + ((cc ^ (rbB & 7)) << 3)]; \
      }                                                                   \
      __builtin_amdgcn_s_setprio(1);                                      \
      _Pragma("unroll") for (int i2 = 0; i2 < 4; ++i2)                    \
          _Pragma("unroll") for (int j2 = 0; j2 < 4; ++j2)                \
          acc[i2][j2] = __builtin_amdgcn_mfma_f32_16x16x32_bf16(          \
              af[i2], bfv[j2], acc[i2][j2], 0, 0, 0);                     \
      __builtin_amdgcn_s_setprio(0);                                      \
    }                                                                     \
  } while (0)

  // ---- prologue: tiles 0,1 in flight; wait only B(0) + A(0)-regs --------
  A_LOAD(ra0, 0);      // vm +8
  B_ISSUE(0, 0);       // vm +4
  A_LOAD(ra1, 1);      // vm +8
  A_STORE(ra0, 0);     // compiler waits ra0 (counted), ds_writes
  __builtin_amdgcn_sched_barrier(0);
  asm volatile("s_waitcnt vmcnt(8) lgkmcnt(0)" ::: "memory");  // allow ra1
  __builtin_amdgcn_s_barrier();
  __builtin_amdgcn_sched_barrier(0);

#pragma unroll
  for (int kt = 0; kt < 7; ++kt) {
    const int cur = kt & 1, nxt = cur ^ 1;
    // issue next-tile B-DMA + store next A-tile + load A(kt+2): 12 new VMEM
    B_ISSUE(nxt, kt + 1);
    if (kt & 1) A_STORE(ra0, nxt);
    else        A_STORE(ra1, nxt);
    if (kt + 2 < 8) {
      if (kt & 1) A_LOAD(ra1, kt + 2);
      else        A_LOAD(ra0, kt + 2);
    }
    __builtin_amdgcn_sched_barrier(0);
    // counted wait: the <=12 newest (this iter's issues) may stay in flight;
    // everything older -- incl. B(cur), A-stores visibility -- is done.
    asm volatile("s_waitcnt vmcnt(12) lgkmcnt(0)" ::: "memory");
    __builtin_amdgcn_s_barrier();
    __builtin_amdgcn_sched_barrier(0);
    COMPUTE(cur);
    __builtin_amdgcn_s_barrier();  // protect buffer 'cur' before next writes
  }
  // ---- tail: tile 7 ----
  asm volatile("s_waitcnt vmcnt(0) lgkmcnt(0)" ::: "memory");
  __builtin_amdgcn_s_barrier();
  __builtin_amdgcn_sched_barrier(0);
  COMPUTE(1);
#undef A_LOAD
#undef A_STORE
#undef B_ISSUE
#undef COMPUTE

  // epilogue: partial write. C/D layout: col=lane&15, row=(lane>>4)*4+reg
  unsigned short* Pp = P + (size_t)ks_split * (8192 * 512);
  const int mb = m0 + wm, nb = n0 + wn;
#pragma unroll
  for (int i = 0; i < 4; ++i)
#pragma unroll
    for (int j = 0; j < 4; ++j) {
      const int row0 = mb + i * 16 + ((lane >> 4) << 2);
      const int col = nb + j * 16 + (lane & 15);
#pragma unroll
      for (int r = 0; r < 4; ++r)
        Pp[(size_t)(row0 + r) * 512 + col] = f2bf(acc[i][j][r]);
    }
}

// ---- k_comb: h=gelu(sum_ks(P0,P1)+bias); out = h@W2 + b2 ---------------
__global__ __launch_bounds__(256) void k_comb(const unsigned short* __restrict__ P,
                                              const unsigned short* __restrict__ W2t,
                                              const float* __restrict__ bias,
                                              const float* __restrict__ b2,
                                              float* __restrict__ out) {
  __shared__ unsigned short W2s[128 * 256];
  __shared__ unsigned short Hs[32 * 256];
  const int wg = blockIdx.x;
  const int b = wg >> 5, jt = wg & 31;
  const int j0 = jt * 32;
  const int t = threadIdx.x;

  {  // stage W2t
    const int row = t >> 1, halfc = (t & 1) * 128;
    const unsigned short* src = W2t + row * 256 + halfc;
    const int cbw = halfc >> 3;
#pragma unroll
    for (int i = 0; i < 16; ++i) {
      short8 v = *(const short8*)(src + i * 8);
      const int c = (cbw + i) ^ (row & 7);
      *(short8*)&W2s[row * 256 + c * 8] = v;
    }
  }
  {  // h rows
    const int r = t >> 3, seg = t & 7;
    const int j = j0 + r;
    const size_t m = (size_t)b * 1024 + j;
    const size_t mp1 = (j < 1023) ? m + 1 : m;
    const float* bs = bias + seg * 32;
    const int cbh = seg * 4;
#pragma unroll
    for (int i = 0; i < 4; ++i) {
      float f0[8];
#pragma unroll
      for (int q = 0; q < 8; ++q) f0[q] = bs[i * 8 + q];
#pragma unroll
      for (int ksp = 0; ksp < 4; ++ksp) {
        const unsigned short* Pk = P + (size_t)ksp * (8192 * 512);
        short8 v0 = *(const short8*)(Pk + m * 512 + seg * 32 + i * 8);
        short8 v1 = *(const short8*)(Pk + mp1 * 512 + 256 + seg * 32 + i * 8);
#pragma unroll
        for (int q = 0; q < 8; ++q)
          f0[q] += bf2f((unsigned short)v0[q]) + bf2f((unsigned short)v1[q]);
      }
      short8 pk;
#pragma unroll
      for (int q = 0; q < 8; ++q) {
        float g = 0.5f * f0[q] * (1.f + erff(f0[q] * 0.70710678118f));
        pk[q] = (short)f2bf(g);
      }
      const int c = (cbh + i) ^ (r & 7);
      *(short8*)&Hs[r * 256 + c * 8] = pk;
    }
  }
  __syncthreads();

  const int wid = t >> 6, lane = t & 63;
  f4 acc[2][2];
#pragma unroll
  for (int i = 0; i < 2; ++i)
#pragma unroll
    for (int j = 0; j < 2; ++j) acc[i][j] = f4{0.f, 0.f, 0.f, 0.f};

#pragma unroll
  for (int ks = 0; ks < 8; ++ks) {
    short8 af[2], bfr[2];
    const int cc = ks * 4 + (lane >> 4);
#pragma unroll
    for (int f = 0; f < 2; ++f) {
      const int ra = f * 16 + (lane & 15);
      af[f] = *(const short8*)&Hs[ra * 256 + ((cc ^ (ra & 7)) << 3)];
      const int rb = wid * 32 + f * 16 + (lane & 15);
      bfr[f] = *(const short8*)&W2s[rb * 256 + ((cc ^ (rb & 7)) << 3)];
    }
#pragma unroll
    for (int i = 0; i < 2; ++i)
#pragma unroll
      for (int j = 0; j < 2; ++j)
        acc[i][j] = __builtin_amdgcn_mfma_f32_16x16x32_bf16(af[i], bfr[j],
                                                            acc[i][j], 0, 0, 0);
  }
#pragma unroll
  for (int i = 0; i < 2; ++i)
#pragma unroll
    for (int j = 0; j < 2; ++j) {
      const int row0 = i * 16 + ((lane >> 4) << 2);
      const int col = wid * 32 + j * 16 + (lane & 15);
      const float bb = b2[col];
#pragma unroll
      for (int r = 0; r < 4; ++r) {
        const int jj = j0 + row0 + r;
        if (jj < 1023)
          out[((size_t)b * 1023 + jj) * 128 + col] = acc[i][j][r] + bb;
      }
    }
}

extern "C" void kernel_launch(void* const* d_in, const int* in_sizes, int n_in,
                              void* d_out, int out_size, void* d_ws, size_t ws_size,
                              hipStream_t stream) {
  const float* x   = (const float*)d_in[0];
  const float* pos = (const float*)d_in[1];
  const float* W1  = (const float*)d_in[2];
  const float* b1  = (const float*)d_in[3];
  const float* W2  = (const float*)d_in[4];
  const float* b2  = (const float*)d_in[5];
  float* out = (float*)d_out;
  char* ws = (char*)d_ws;
  unsigned short* Bt  = (unsigned short*)(ws + OFF_BT);
  unsigned short* W2t = (unsigned short*)(ws + OFF_W2T);
  float* part         = (float*)(ws + OFF_PART);
  float* bias         = (float*)(ws + OFF_BIAS);
  unsigned short* P   = (unsigned short*)(ws + OFF_P);

  k_prep<<<384, 256, 0, stream>>>(W1, pos, W2, Bt, W2t, part);
  k_bias<<<1, 256, 0, stream>>>(b1, part, bias);
  k_gemm<<<1024, 256, 0, stream>>>(x, Bt, P);
  k_comb<<<256, 256, 0, stream>>>(P, W2t, bias, b2, out);
}

// Round 6
// 59.925 us; speedup vs baseline: 1.2245x; 1.2245x over previous
//
#include <hip/hip_runtime.h>
#include <hip/hip_bf16.h>
#include <math.h>

// TokenCompressor: B=8, N=16384, C=128, BLOCK=32, STRIDE=16 -> nb=1023
// Decomposition: chunks c of 16 tokens; A = x.view(8192, 2048) (contiguous!)
//   P[m, 0:256]  = chunk[m] @ W1[0:2048]
//   P[m, 256:512]= chunk[m] @ W1[2048:4096]
//   h[j] = gelu(P[j,0:256] + P[j+1,256:512] + b1 + posflat@W1)
//   out[j] = h[j] @ W2 + b2
// R6: R2-R5 all ~313 TF; common element = in-loop f32->bf16 reg staging of A
// (VGPR_Count 88 proves the 2-ahead prefetch was compiled away -> serial L3
// latency each K-step). Now BOTH operands go global_load_lds (A as f32, cvt
// at fragment read via v_cvt_pk_bf16_f32), 3-deep LDS buffer pipeline with
// counted vmcnt(12), BK=32, 2 blocks/CU, split-K=4.

typedef __attribute__((ext_vector_type(8))) short short8;
typedef __attribute__((ext_vector_type(4))) float f4;

#define OFF_BT   0u                          // 512x2048 bf16 = 2 MB
#define OFF_W2T  (2u << 20)                  // 128x256 bf16 = 64 KB
#define OFF_PART ((2u << 20) + (64u << 10))  // 64x256 f32 = 64 KB
#define OFF_BIAS ((2u << 20) + (128u << 10)) // 256 f32
#define OFF_P    (4u << 20)                  // 4 x (8192x512) bf16 = 32 MB

static __device__ __forceinline__ unsigned short f2bf(float f) {
  union { float f; unsigned u; } v; v.f = f;
  return (unsigned short)((v.u + 0x7FFFu + ((v.u >> 16) & 1u)) >> 16);
}
static __device__ __forceinline__ float bf2f(unsigned short h) {
  union { unsigned u; float f; } v; v.u = ((unsigned)h) << 16;
  return v.f;
}
static __device__ __forceinline__ void gload_lds16(const void* g, void* l) {
  __builtin_amdgcn_global_load_lds(
      (const __attribute__((address_space(1))) void*)g,
      (__attribute__((address_space(3))) void*)l, 16, 0, 0);
}

// ---- k_prep: blocks 0..255: W1 -> Bt (512x2048 bf16, n-major) + bias parts
//              blocks 256..383: W2 (256x128 f32) -> W2t (128x256 bf16, T)
__global__ __launch_bounds__(256) void k_prep(const float* __restrict__ W1,
                                              const float* __restrict__ pos,
                                              const float* __restrict__ W2,
                                              unsigned short* __restrict__ Bt,
                                              unsigned short* __restrict__ W2t,
                                              float* __restrict__ part) {
  __shared__ float T[64][65];
  const int w = blockIdx.x;
  const int t = threadIdx.x;
  if (w >= 256) {
    const int n = w - 256;
    W2t[n * 256 + t] = f2bf(W2[t * 128 + n]);
    return;
  }
  const int h = w >> 7, rem = w & 127, kt = rem >> 2, nt = rem & 3;
  const int krow0 = h * 2048 + kt * 64, col0 = nt * 64;
  const int lr = t >> 2, lc = (t & 3) * 16;
  const float* src = W1 + (size_t)(krow0 + lr) * 256 + col0 + lc;
#pragma unroll
  for (int i = 0; i < 4; ++i) {
    f4 v = *(const f4*)(src + i * 4);
#pragma unroll
    for (int q = 0; q < 4; ++q) T[lr][lc + i * 4 + q] = v[q];
  }
  __syncthreads();
  if (t < 64) {
    float s = 0.f;
#pragma unroll 8
    for (int k = 0; k < 64; ++k) s += T[k][t] * pos[krow0 + k];
    part[(h * 32 + kt) * 256 + col0 + t] = s;
  }
  const int nl = t >> 2, kc = (t & 3) * 16;
  short8 o0, o1;
#pragma unroll
  for (int i = 0; i < 8; ++i) o0[i] = (short)f2bf(T[kc + i][nl]);
#pragma unroll
  for (int i = 0; i < 8; ++i) o1[i] = (short)f2bf(T[kc + 8 + i][nl]);
  unsigned short* dst = Bt + (size_t)(256 * h + col0 + nl) * 2048 + kt * 64 + kc;
  *(short8*)dst = o0;
  *(short8*)(dst + 8) = o1;
}

// ---- k_bias ------------------------------------------------------------
__global__ __launch_bounds__(256) void k_bias(const float* __restrict__ b1,
                                              const float* __restrict__ part,
                                              float* __restrict__ bias) {
  int n = threadIdx.x;
  float s = b1[n];
#pragma unroll 8
  for (int g = 0; g < 64; ++g) s += part[g * 256 + n];
  bias[n] = s;
}

// ---- k_gemm: Ppart[ks] (8192x512 bf16) = A(f32)[:,ks*512:+512] @ Bt^T ----
// 128x128 tile, BK=32, NT=16. 4 waves x (64x64). 1024 wgs, 2 blocks/CU.
// 3-deep global_load_lds pipeline, counted vmcnt, conversion at frag read.
// LDS per buffer: A 128x32 f32 (16KB, row=128B=8 chunks, chunk^=(row&7)),
//                 B 128x32 bf16 (8KB, row=64B=4 chunks, chunk^=(row&3)).
__global__ __launch_bounds__(256, 2) void k_gemm(const float* __restrict__ X,
                                                 const unsigned short* __restrict__ Bt,
                                                 unsigned short* __restrict__ P) {
  __shared__ __align__(16) char ldsbuf[3][24576];
  const int orig = blockIdx.x;
  const int wg = (orig & 7) * 128 + (orig >> 3);  // 1024 % 8 == 0 -> bijective
  const int mt = wg >> 4;                 // 0..63  (same mt -> same XCD)
  const int nt = (wg >> 2) & 3;           // 0..3
  const int ks_split = wg & 3;            // 0..3
  const int m0 = mt * 128, n0 = nt * 128;
  const int k0 = ks_split * 512;
  const int t = threadIdx.x;
  const int wid = t >> 6, lane = t & 63;
  const int wm = (wid >> 1) * 64, wn = (wid & 1) * 64;

  f4 acc[4][4];
#pragma unroll
  for (int i = 0; i < 4; ++i)
#pragma unroll
    for (int j = 0; j < 4; ++j) acc[i][j] = f4{0.f, 0.f, 0.f, 0.f};

  // 6 DMA issues per thread per tile (4 A + 2 B)
#define ISSUE(BUF, KT)                                                     \
  do {                                                                     \
    const int kbase = k0 + (KT) * 32;                                      \
    _Pragma("unroll") for (int ii = 0; ii < 4; ++ii) {                     \
      const int row = wid * 32 + ii * 8 + (lane >> 3);                     \
      const int g = (lane & 7) ^ (row & 7);                                \
      const float* srcA = X + (size_t)(m0 + row) * 2048 + kbase + g * 4;   \
      gload_lds16(srcA, &ldsbuf[BUF][wid * 4096 + ii * 1024]);             \
    }                                                                      \
    _Pragma("unroll") for (int ii = 0; ii < 2; ++ii) {                     \
      const int rowb = ii * 64 + wid * 16 + (lane >> 2);                   \
      const int gb = (lane & 3) ^ (rowb & 3);                              \
      const unsigned short* srcB =                                         \
          Bt + (size_t)(n0 + rowb) * 2048 + kbase + gb * 8;                \
      gload_lds16(srcB, &ldsbuf[BUF][16384 + ii * 4096 + wid * 1024]);     \
    }                                                                      \
  } while (0)

#define COMPUTE(BUF)                                                       \
  do {                                                                     \
    const float* Ab = (const float*)&ldsbuf[BUF][0];                       \
    const unsigned short* Bb = (const unsigned short*)&ldsbuf[BUF][16384]; \
    short8 af[4], bfv[4];                                                  \
    _Pragma("unroll") for (int f = 0; f < 4; ++f) {                        \
      const int rowA = wm + f * 16 + (lane & 15);                          \
      const int c0 = (lane >> 4) * 2;                                      \
      f4 lo = *(const f4*)(Ab + rowA * 32 + ((c0 ^ (rowA & 7)) << 2));     \
      f4 hi = *(const f4*)(Ab + rowA * 32 + (((c0 + 1) ^ (rowA & 7)) << 2));\
      union { short8 s; unsigned u[4]; } pkv;                              \
      asm("v_cvt_pk_bf16_f32 %0, %1, %2" : "=v"(pkv.u[0])                  \
          : "v"(lo[0]), "v"(lo[1]));                                       \
      asm("v_cvt_pk_bf16_f32 %0, %1, %2" : "=v"(pkv.u[1])                  \
          : "v"(lo[2]), "v"(lo[3]));                                       \
      asm("v_cvt_pk_bf16_f32 %0, %1, %2" : "=v"(pkv.u[2])                  \
          : "v"(hi[0]), "v"(hi[1]));                                       \
      asm("v_cvt_pk_bf16_f32 %0, %1, %2" : "=v"(pkv.u[3])                  \
          : "v"(hi[2]), "v"(hi[3]));                                       \
      af[f] = pkv.s;                                                       \
      const int rowB = wn + f * 16 + (lane & 15);                          \
      const int cB = lane >> 4;                                            \
      bfv[f] = *(const short8*)(Bb + rowB * 32 + ((cB ^ (rowB & 3)) << 3));\
    }                                                                      \
    __builtin_amdgcn_s_setprio(1);                                         \
    _Pragma("unroll") for (int i2 = 0; i2 < 4; ++i2)                       \
        _Pragma("unroll") for (int j2 = 0; j2 < 4; ++j2)                   \
        acc[i2][j2] = __builtin_amdgcn_mfma_f32_16x16x32_bf16(             \
            af[i2], bfv[j2], acc[i2][j2], 0, 0, 0);                        \
    __builtin_amdgcn_s_setprio(0);                                         \
  } while (0)

  // ---- prologue: 3 tiles in flight, wait for tile 0 (12 = 2 tiles left) --
  ISSUE(0, 0);
  ISSUE(1, 1);
  ISSUE(2, 2);
  __builtin_amdgcn_sched_barrier(0);
  asm volatile("s_waitcnt vmcnt(12)" ::: "memory");
  __builtin_amdgcn_s_barrier();
  __builtin_amdgcn_sched_barrier(0);

#pragma unroll
  for (int kt = 0; kt < 16; ++kt) {
    COMPUTE(kt % 3);
    __builtin_amdgcn_s_barrier();          // all waves done reading buf kt%3
    __builtin_amdgcn_sched_barrier(0);
    if (kt + 3 < 16) ISSUE(kt % 3, kt + 3);
    if (kt < 15) {
      __builtin_amdgcn_sched_barrier(0);
      if (kt < 13)       asm volatile("s_waitcnt vmcnt(12)" ::: "memory");
      else if (kt == 13) asm volatile("s_waitcnt vmcnt(6)" ::: "memory");
      else               asm volatile("s_waitcnt vmcnt(0)" ::: "memory");
      __builtin_amdgcn_s_barrier();
      __builtin_amdgcn_sched_barrier(0);
    }
  }
#undef ISSUE
#undef COMPUTE

  // epilogue: partial write. C/D layout: col=lane&15, row=(lane>>4)*4+reg
  unsigned short* Pp = P + (size_t)ks_split * (8192 * 512);
  const int mb = m0 + wm, nb = n0 + wn;
#pragma unroll
  for (int i = 0; i < 4; ++i)
#pragma unroll
    for (int j = 0; j < 4; ++j) {
      const int row0 = mb + i * 16 + ((lane >> 4) << 2);
      const int col = nb + j * 16 + (lane & 15);
#pragma unroll
      for (int r = 0; r < 4; ++r)
        Pp[(size_t)(row0 + r) * 512 + col] = f2bf(acc[i][j][r]);
    }
}

// ---- k_comb: h=gelu(sum_ks(P0,P1)+bias); out = h@W2 + b2 ---------------
__global__ __launch_bounds__(256) void k_comb(const unsigned short* __restrict__ P,
                                              const unsigned short* __restrict__ W2t,
                                              const float* __restrict__ bias,
                                              const float* __restrict__ b2,
                                              float* __restrict__ out) {
  __shared__ unsigned short W2s[128 * 256];
  __shared__ unsigned short Hs[32 * 256];
  const int wg = blockIdx.x;
  const int b = wg >> 5, jt = wg & 31;
  const int j0 = jt * 32;
  const int t = threadIdx.x;

  {  // stage W2t
    const int row = t >> 1, halfc = (t & 1) * 128;
    const unsigned short* src = W2t + row * 256 + halfc;
    const int cbw = halfc >> 3;
#pragma unroll
    for (int i = 0; i < 16; ++i) {
      short8 v = *(const short8*)(src + i * 8);
      const int c = (cbw + i) ^ (row & 7);
      *(short8*)&W2s[row * 256 + c * 8] = v;
    }
  }
  {  // h rows
    const int r = t >> 3, seg = t & 7;
    const int j = j0 + r;
    const size_t m = (size_t)b * 1024 + j;
    const size_t mp1 = (j < 1023) ? m + 1 : m;
    const float* bs = bias + seg * 32;
    const int cbh = seg * 4;
#pragma unroll
    for (int i = 0; i < 4; ++i) {
      float f0[8];
#pragma unroll
      for (int q = 0; q < 8; ++q) f0[q] = bs[i * 8 + q];
#pragma unroll
      for (int ksp = 0; ksp < 4; ++ksp) {
        const unsigned short* Pk = P + (size_t)ksp * (8192 * 512);
        short8 v0 = *(const short8*)(Pk + m * 512 + seg * 32 + i * 8);
        short8 v1 = *(const short8*)(Pk + mp1 * 512 + 256 + seg * 32 + i * 8);
#pragma unroll
        for (int q = 0; q < 8; ++q)
          f0[q] += bf2f((unsigned short)v0[q]) + bf2f((unsigned short)v1[q]);
      }
      short8 pk;
#pragma unroll
      for (int q = 0; q < 8; ++q) {
        float g = 0.5f * f0[q] * (1.f + erff(f0[q] * 0.70710678118f));
        pk[q] = (short)f2bf(g);
      }
      const int c = (cbh + i) ^ (r & 7);
      *(short8*)&Hs[r * 256 + c * 8] = pk;
    }
  }
  __syncthreads();

  const int wid = t >> 6, lane = t & 63;
  f4 acc[2][2];
#pragma unroll
  for (int i = 0; i < 2; ++i)
#pragma unroll
    for (int j = 0; j < 2; ++j) acc[i][j] = f4{0.f, 0.f, 0.f, 0.f};

#pragma unroll
  for (int ks = 0; ks < 8; ++ks) {
    short8 af[2], bfr[2];
    const int cc = ks * 4 + (lane >> 4);
#pragma unroll
    for (int f = 0; f < 2; ++f) {
      const int ra = f * 16 + (lane & 15);
      af[f] = *(const short8*)&Hs[ra * 256 + ((cc ^ (ra & 7)) << 3)];
      const int rb = wid * 32 + f * 16 + (lane & 15);
      bfr[f] = *(const short8*)&W2s[rb * 256 + ((cc ^ (rb & 7)) << 3)];
    }
#pragma unroll
    for (int i = 0; i < 2; ++i)
#pragma unroll
      for (int j = 0; j < 2; ++j)
        acc[i][j] = __builtin_amdgcn_mfma_f32_16x16x32_bf16(af[i], bfr[j],
                                                            acc[i][j], 0, 0, 0);
  }
#pragma unroll
  for (int i = 0; i < 2; ++i)
#pragma unroll
    for (int j = 0; j < 2; ++j) {
      const int row0 = i * 16 + ((lane >> 4) << 2);
      const int col = wid * 32 + j * 16 + (lane & 15);
      const float bb = b2[col];
#pragma unroll
      for (int r = 0; r < 4; ++r) {
        const int jj = j0 + row0 + r;
        if (jj < 1023)
          out[((size_t)b * 1023 + jj) * 128 + col] = acc[i][j][r] + bb;
      }
    }
}

extern "C" void kernel_launch(void* const* d_in, const int* in_sizes, int n_in,
                              void* d_out, int out_size, void* d_ws, size_t ws_size,
                              hipStream_t stream) {
  const float* x   = (const float*)d_in[0];
  const float* pos = (const float*)d_in[1];
  const float* W1  = (const float*)d_in[2];
  const float* b1  = (const float*)d_in[3];
  const float* W2  = (const float*)d_in[4];
  const float* b2  = (const float*)d_in[5];
  float* out = (float*)d_out;
  char* ws = (char*)d_ws;
  unsigned short* Bt  = (unsigned short*)(ws + OFF_BT);
  unsigned short* W2t = (unsigned short*)(ws + OFF_W2T);
  float* part         = (float*)(ws + OFF_PART);
  float* bias         = (float*)(ws + OFF_BIAS);
  unsigned short* P   = (unsigned short*)(ws + OFF_P);

  k_prep<<<384, 256, 0, stream>>>(W1, pos, W2, Bt, W2t, part);
  k_bias<<<1, 256, 0, stream>>>(b1, part, bias);
  k_gemm<<<1024, 256, 0, stream>>>(x, Bt, P);
  k_comb<<<256, 256, 0, stream>>>(P, W2t, bias, b2, out);
}